// Round 10
// baseline (383.342 us; speedup 1.0000x reference)
//
#include <hip/hip_runtime.h>
#include <hip/hip_bf16.h>
#include <stdint.h>

#define BB 4
#define NN 4096
#define DD 128
#define BI 32   // i-rows per block (32 -> 512 blocks -> 2 blocks/CU for TLP stall hiding)
#define BJ 64   // j (K) per staged tile
#define NT (NN / BJ)

typedef _Float16 f16;
typedef __attribute__((ext_vector_type(4))) _Float16 f16x4;
typedef __attribute__((ext_vector_type(8))) _Float16 f16x8;
typedef __attribute__((ext_vector_type(4))) float f32x4;

typedef __attribute__((address_space(3))) uint32_t lds_u32_t;
typedef const __attribute__((address_space(1))) uint32_t glb_u32_t;

__device__ __forceinline__ void gload_lds16(const void* g, void* l) {
    __builtin_amdgcn_global_load_lds((glb_u32_t*)g, (lds_u32_t*)l, 16, 0, 0);
}

// ---------------- prep: x[b][j][d] -> xt fp16 [b][d][j] (unchanged, proven) ----------------
__global__ void prep_xt(const float* __restrict__ x, f16* __restrict__ xt) {
    __shared__ float tile[32][33];
    int bid = blockIdx.x;
    int b = bid >> 9;
    int rest = bid & 511;
    int j0 = (rest >> 2) * 32;
    int d0 = (rest & 3) * 32;
    int t = threadIdx.x;
#pragma unroll
    for (int p = 0; p < 4; ++p) {
        int idx = p * 256 + t;
        int jj = idx >> 5, dd = idx & 31;
        tile[jj][dd] = x[((size_t)b * NN + j0 + jj) * DD + d0 + dd];
    }
    __syncthreads();
#pragma unroll
    for (int p = 0; p < 4; ++p) {
        int idx = p * 256 + t;
        int dd = idx >> 5, jj = idx & 31;
        xt[((size_t)b * DD + d0 + dd) * NN + j0 + jj] = (f16)tile[jj][dd];
    }
}

// ---------------- prep: U[d][e] -> ut fp16 [e][d] (unchanged, proven) ----------------
__global__ void prep_ut(const float* __restrict__ U, f16* __restrict__ ut) {
    __shared__ float tile[32][33];
    int bid = blockIdx.x;
    int d0 = (bid >> 2) * 32, e0 = (bid & 3) * 32;
    int t = threadIdx.x;
#pragma unroll
    for (int p = 0; p < 4; ++p) {
        int idx = p * 256 + t;
        int dd = idx >> 5, ee = idx & 31;
        tile[dd][ee] = U[(size_t)(d0 + dd) * DD + e0 + ee];
    }
    __syncthreads();
#pragma unroll
    for (int p = 0; p < 4; ++p) {
        int idx = p * 256 + t;
        int ee = idx >> 5, dd = idx & 31;
        ut[(size_t)(e0 + ee) * DD + d0 + dd] = (f16)tile[dd][ee];
    }
}

// ---------------- fused: agg (masked adj^T @ x) + deg + (agg@U)/deg + relu ----------------
// 512 blocks (b, i0), 512 threads (8 waves), 2 blocks/CU. Tile 32 i x 128 d, K-step 64 j.
// Same T14 structure as the BI=64 version; independent barrier domains hide the
// per-step vmcnt drain stall across blocks.
__global__ __launch_bounds__(512, 4) void fused_kernel(
    const float* __restrict__ adj, const f16* __restrict__ xt,
    const f16* __restrict__ ut, float* __restrict__ out)
{
    __shared__ __align__(16) f16 mlds[2][BI * BJ];   // mask [i][j], 4KB each
    __shared__ __align__(16) f16 xlds[2][DD * BJ];   // xT [d][j], 16KB each
    __shared__ float degl[16][BI];                   // 2KB
    __shared__ float degs[BI];

    const int t = threadIdx.x;
    const int w = t >> 6;    // wave 0..7
    const int l = t & 63;
    const int bid = blockIdx.x;
    const int b = bid >> 7;              // 128 blocks per batch
    const int i0 = (bid & 127) * BI;

    const float* adjb = adj + (size_t)b * NN * NN + i0;
    const f16* xtb = xt + (size_t)b * DD * NN;

    // staging map: thread stages 4 j for row si, j-group jg (16 groups x 4 j = 64 j)
    const int si = l & 31;
    const int jg = w * 2 + (l >> 5);
    const int physu = (jg >> 1) ^ ((si >> 1) & 7);       // unit swizzle (row stride 8 units)
    const int mwoff = (si * 8 + physu) * 8 + (jg & 1) * 4;

    const int iw = w & 1;          // wave's i-frag (rows iw*16..)
    const int dq = w >> 1;         // wave's d-quarter (cols dq*32..)

    f32x4 acc[2] = {f32x4{0,0,0,0}, f32x4{0,0,0,0}};
    float degp = 0.f;
    float v[4];

    auto load_adj = [&](int jt) {
        const float* src = adjb + (size_t)(jt * BJ + jg * 4) * NN + si;
#pragma unroll
        for (int q = 0; q < 4; ++q) v[q] = src[(size_t)q * NN];
    };
    auto dma_xt = [&](int jt, int buf) {
        const int j0 = jt * BJ;
#pragma unroll
        for (int c = 0; c < 2; ++c) {
            int g = (w * 2 + c) * 64 + l;     // linear 16B-unit index (1024 units)
            int d = g >> 3, ul = g & 7;
            int ug = ul ^ ((d >> 1) & 7);     // pre-swizzled source (rule #21)
            gload_lds16(xtb + (size_t)d * NN + j0 + ug * 8, &xlds[buf][(size_t)g * 8]);
        }
    };
    auto convert_write = [&](int buf) {
        f16x4 m4;
#pragma unroll
        for (int q = 0; q < 4; ++q) {
            degp += v[q];
            m4[q] = v[q] > 0.f ? (f16)1.f : (f16)0.f;
        }
        *(f16x4*)&mlds[buf][mwoff] = m4;
    };
    auto compute = [&](int buf) {
#pragma unroll
        for (int kk = 0; kk < 2; ++kk) {
            const int row = iw * 16 + (l & 15);
            const int ug = kk * 4 + (l >> 4);
            f16x8 a = *(const f16x8*)&mlds[buf][(row * 8 + (ug ^ ((row >> 1) & 7))) * 8];
#pragma unroll
            for (int f = 0; f < 2; ++f) {
                const int d = dq * 32 + f * 16 + (l & 15);
                f16x8 bb = *(const f16x8*)&xlds[buf][(d * 8 + (ug ^ ((d >> 1) & 7))) * 8];
                acc[f] = __builtin_amdgcn_mfma_f32_16x16x32_f16(a, bb, acc[f], 0, 0, 0);
            }
        }
    };

    // prologue: tile 0
    load_adj(0);
    dma_xt(0, 0);
    convert_write(0);
    __syncthreads();

    for (int jt = 0; jt < NT; ++jt) {
        const int cur = jt & 1;
        if (jt + 1 < NT) {
            load_adj(jt + 1);            // issue early (T14)
            dma_xt(jt + 1, cur ^ 1);
        }
        compute(cur);                    // independent of v — hides load latency
        if (jt + 1 < NT) convert_write(cur ^ 1);  // vmcnt wait lands here
        __syncthreads();
    }

    // ---- epilogue: out = relu((agg @ U) / deg) ----
    degl[jg][si] = degp;
    __syncthreads();                     // all K-loop LDS reads done; buffers free

    f16* alds = &mlds[0][0];             // 8KB: agg f16 [row][16 units], swz u^(row&7)
    f16* ulds = &xlds[0][0];             // 32KB: U^T [e][16 units], swz u^(e&7)

    // stage U^T via DMA (2048 units, 4/thread), pre-swizzled source
#pragma unroll
    for (int c = 0; c < 4; ++c) {
        int g = (w * 4 + c) * 64 + l;
        int e = g >> 4, ul = g & 15;
        int ug = ul ^ (e & 7);
        gload_lds16(ut + (size_t)e * DD + ug * 8, &ulds[(size_t)g * 8]);
    }
    // acc -> alds (f16, swizzled scalar writes; one-time cost)
#pragma unroll
    for (int f = 0; f < 2; ++f) {
#pragma unroll
        for (int r = 0; r < 4; ++r) {
            int row = iw * 16 + (l >> 4) * 4 + r;
            int col = dq * 32 + f * 16 + (l & 15);
            alds[(row * 16 + ((col >> 3) ^ (row & 7))) * 8 + (col & 7)] = (f16)acc[f][r];
        }
    }
    if (t < BI) {
        float s = 0.f;
#pragma unroll
        for (int q = 0; q < 16; ++q) s += degl[q][t];
        degs[t] = s;
    }
    __syncthreads();                     // drains DMA + ds writes

    // wave w: i-frag iw2 = w&1, e-block ebase = (w>>1)*32 (2 e-frags)
    const int iw2 = w & 1;
    const int ebase = (w >> 1) * 32;
    f32x4 acc2[2] = {f32x4{0,0,0,0}, f32x4{0,0,0,0}};
#pragma unroll
    for (int kk = 0; kk < 4; ++kk) {
        const int row = iw2 * 16 + (l & 15);
        const int ug = kk * 4 + (l >> 4);
        f16x8 a = *(const f16x8*)&alds[(row * 16 + (ug ^ (row & 7))) * 8];
#pragma unroll
        for (int ef = 0; ef < 2; ++ef) {
            const int e = ebase + ef * 16 + (l & 15);
            f16x8 bb = *(const f16x8*)&ulds[(e * 16 + (ug ^ (e & 7))) * 8];
            acc2[ef] = __builtin_amdgcn_mfma_f32_16x16x32_f16(a, bb, acc2[ef], 0, 0, 0);
        }
    }

    float rdeg[4];
#pragma unroll
    for (int r = 0; r < 4; ++r)
        rdeg[r] = 1.0f / degs[iw2 * 16 + (l >> 4) * 4 + r];

    float* outb = out + ((size_t)b * NN + i0) * DD;
#pragma unroll
    for (int ef = 0; ef < 2; ++ef) {
#pragma unroll
        for (int r = 0; r < 4; ++r) {
            int row = iw2 * 16 + (l >> 4) * 4 + r;
            int e = ebase + ef * 16 + (l & 15);
            float vv = acc2[ef][r] * rdeg[r];
            outb[(size_t)row * DD + e] = vv > 0.f ? vv : 0.f;
        }
    }
}

extern "C" void kernel_launch(void* const* d_in, const int* in_sizes, int n_in,
                              void* d_out, int out_size, void* d_ws, size_t ws_size,
                              hipStream_t stream) {
    const float* x   = (const float*)d_in[0];
    const float* adj = (const float*)d_in[1];
    const float* U   = (const float*)d_in[2];
    float* out = (float*)d_out;

    char* ws = (char*)d_ws;
    f16* xt = (f16*)ws;                                   // 4 MB
    f16* ut = (f16*)(ws + (size_t)BB * DD * NN * 2);      // 32 KB

    hipLaunchKernelGGL(prep_xt, dim3(BB * (NN / 32) * (DD / 32)), dim3(256), 0, stream, x, xt);
    hipLaunchKernelGGL(prep_ut, dim3((DD / 32) * (DD / 32)), dim3(256), 0, stream, U, ut);
    hipLaunchKernelGGL(fused_kernel, dim3(BB * (NN / BI)), dim3(512), 0, stream, adj, xt, ut, out);
}